// Round 14
// baseline (176.852 us; speedup 1.0000x reference)
//
#include <hip/hip_runtime.h>
#include <hip/hip_fp16.h>
#include <math.h>

#define N_NODES 50000
#define N_EDGES 640000
#define HDIM    128
#define D_OUT   64
#define G_GRAPHS 500
#define EPSV    1e-5f
#define WPM     16384   // elements per packed 128x128 weight matrix
#define CAP     64      // bucket capacity (mean deg 12.8, P(deg>=64)~1e-24)
#define SENT    N_NODES // sentinel src id -> zero phantom row, cnt[SENT]=0
#define NSHARD  8       // dst shards, aligned with 8 XCDs (blockIdx%8 hint)
#define SHARD_SZ ((N_NODES + NSHARD - 1) / NSHARD)   // 6250

typedef __bf16 v8bf __attribute__((ext_vector_type(8)));
typedef float  f32x4 __attribute__((ext_vector_type(4)));

static __device__ __forceinline__ float bf_lo(unsigned u) {
    union { unsigned x; float f; } c; c.x = u << 16; return c.f;
}
static __device__ __forceinline__ float bf_hi(unsigned u) {
    union { unsigned x; float f; } c; c.x = u & 0xffff0000u; return c.f;
}

// ---------------------------------------------------------------------------
// Setup: zero cnt (incl. cnt[SENT]) + pooled, zero phantom h rows, AND pack
// 7 f32 128x128 weights into bf16 MFMA B-fragment order with conv-softmax
// folded in:
//   m=0: pre_w   m=1,2: wc0[l]*gcn_w[l]  m=3,4: wc1[l]*sage_ws[l]
//   m=5,6: wc1[l]*sage_wn[l]
// ---------------------------------------------------------------------------
__global__ void setup_kernel(const float* __restrict__ pre_w,
                             const float* __restrict__ gcn_w,
                             const float* __restrict__ sws,
                             const float* __restrict__ swn,
                             const float* __restrict__ a_conv,
                             __bf16* __restrict__ Wp,
                             int* __restrict__ cnt,
                             float* __restrict__ pooled,
                             uint4* __restrict__ hrow0,
                             uint4* __restrict__ hrow1)
{
    int t = blockIdx.x * blockDim.x + threadIdx.x;
    if (t <= N_NODES) cnt[t] = 0;             // includes sentinel slot
    if (t < G_GRAPHS * 128) pooled[t] = 0.f;
    if (t < 16) {  // zero phantom row N of hb0 and h1b (256B each)
        hrow0[t] = make_uint4(0, 0, 0, 0);
        hrow1[t] = make_uint4(0, 0, 0, 0);
    }
    if (t >= 7 * 2048) return;
    int m    = t >> 11;
    int r    = t & 2047;
    int lane = r & 63;
    int fb   = r >> 6;           // kc*8 + cb
    int kc   = fb >> 3;
    int cb   = fb & 7;
    const float* W = pre_w;
    float scale = 1.f;
    if (m > 0) {
        int type = (m - 1) >> 1;     // 0=gcn, 1=sage_ws, 2=sage_wn
        int l    = (m - 1) & 1;
        float c0 = a_conv[l * 2], c1 = a_conv[l * 2 + 1];
        float mx = fmaxf(c0, c1);
        float e0 = __expf(c0 - mx), e1 = __expf(c1 - mx);
        float wc0 = e0 / (e0 + e1);
        scale = (type == 0) ? wc0 : (1.f - wc0);
        W = (type == 0) ? gcn_w + (size_t)l * WPM
          : (type == 1) ? sws   + (size_t)l * WPM
                        : swn   + (size_t)l * WPM;
    }
    int k0  = kc * 32 + (lane >> 4) * 8;
    int col = cb * 16 + (lane & 15);
    __bf16* out = Wp + (size_t)m * WPM + ((size_t)fb * 64 + lane) * 8;
    #pragma unroll
    for (int i = 0; i < 8; i++)
        out[i] = (__bf16)(scale * W[(size_t)(k0 + i) * 128 + col]);
}

// ---------------------------------------------------------------------------
// XCD-sharded direct-bucket CSR fill (2-byte entries, no counting pass).
// Blocks 8i..8i+7 process edge chunk i; block 8i+s writes only dst-shard s.
// ---------------------------------------------------------------------------
__global__ void csr_fill_kernel(const int* __restrict__ src, const int* __restrict__ dst,
                                int* __restrict__ cnt,
                                unsigned short* __restrict__ csr, int E) {
    int chunk = blockIdx.x >> 3;
    int shard = blockIdx.x & 7;
    int e = chunk * 256 + threadIdx.x;
    if (e >= E) return;
    int d = dst[e];
    if (d / SHARD_SZ != shard) return;
    int s = src[e];
    int pos = atomicAdd(&cnt[d], 1);
    csr[(d << 6) + pos] = (unsigned short)s;
}

// ---------------------------------------------------------------------------
// Pull-gather (bf16): one wave per dst node, direct buckets, unmasked main
// loop + single masked tail iteration (no sentinel prefill needed).
// dinv computed inline from the hot cnt table (no fp16 side table).
// ---------------------------------------------------------------------------
__global__ __launch_bounds__(256) void fused_gather_bf16(
    const __bf16* __restrict__ hb,
    const unsigned short* __restrict__ csr,
    const int* __restrict__ cnt,
    __bf16* __restrict__ aggGb,
    __bf16* __restrict__ meanb, int n)
{
    int w = threadIdx.x >> 6;
    int lane = threadIdx.x & 63;
    int d = blockIdx.x * 4 + w;
    if (d >= n) return;
    int c = cnt[d];
    float cf = (float)c;
    float did = rsqrtf(cf + 1.0f);
    float rd  = 1.0f / fmaxf(cf, 1.0f);
    int base = d << 6;
    int full = c >> 4;          // unmasked 16-edge iterations
    int q  = lane >> 4;
    int c8 = (lane & 15) * 8;

    float aG[8] = {0, 0, 0, 0, 0, 0, 0, 0};
    float aS[8] = {0, 0, 0, 0, 0, 0, 0, 0};

    for (int p = 0; p < full; p++) {
        int s[4];
        #pragma unroll
        for (int k = 0; k < 4; k++)
            s[k] = csr[base + p * 16 + 4 * k + q];
        uint4 u[4];
        float ds[4];
        #pragma unroll
        for (int k = 0; k < 4; k++) {
            u[k]  = *(const uint4*)(hb + (size_t)s[k] * 128 + c8);
            ds[k] = rsqrtf((float)cnt[s[k]] + 1.0f);
        }
        #pragma unroll
        for (int k = 0; k < 4; k++) {
            float wk = ds[k] * did;
            float v[8] = { bf_lo(u[k].x), bf_hi(u[k].x), bf_lo(u[k].y), bf_hi(u[k].y),
                           bf_lo(u[k].z), bf_hi(u[k].z), bf_lo(u[k].w), bf_hi(u[k].w) };
            #pragma unroll
            for (int j = 0; j < 8; j++) {
                aG[j] = fmaf(v[j], wk, aG[j]);
                aS[j] += v[j];
            }
        }
    }
    if (c & 15) {   // masked tail: SENT -> zero phantom row, cnt[SENT]=0
        int s[4];
        #pragma unroll
        for (int k = 0; k < 4; k++) {
            int idx = full * 16 + 4 * k + q;
            s[k] = (idx < c) ? (int)csr[base + idx] : SENT;
        }
        uint4 u[4];
        float ds[4];
        #pragma unroll
        for (int k = 0; k < 4; k++) {
            u[k]  = *(const uint4*)(hb + (size_t)s[k] * 128 + c8);
            ds[k] = rsqrtf((float)cnt[s[k]] + 1.0f);
        }
        #pragma unroll
        for (int k = 0; k < 4; k++) {
            float wk = ds[k] * did;
            float v[8] = { bf_lo(u[k].x), bf_hi(u[k].x), bf_lo(u[k].y), bf_hi(u[k].y),
                           bf_lo(u[k].z), bf_hi(u[k].z), bf_lo(u[k].w), bf_hi(u[k].w) };
            #pragma unroll
            for (int j = 0; j < 8; j++) {
                aG[j] = fmaf(v[j], wk, aG[j]);
                aS[j] += v[j];
            }
        }
    }
    #pragma unroll
    for (int j = 0; j < 8; j++) {
        aG[j] += __shfl_xor(aG[j], 16);
        aG[j] += __shfl_xor(aG[j], 32);
        aS[j] += __shfl_xor(aS[j], 16);
        aS[j] += __shfl_xor(aS[j], 32);
    }
    if (q == 0) {
        uint4 ud = *(const uint4*)(hb + (size_t)d * 128 + c8);
        float vd[8] = { bf_lo(ud.x), bf_hi(ud.x), bf_lo(ud.y), bf_hi(ud.y),
                        bf_lo(ud.z), bf_hi(ud.z), bf_lo(ud.w), bf_hi(ud.w) };
        float sl = did * did;
        union { __bf16 b[8]; uint4 u; } pg, pm;
        #pragma unroll
        for (int j = 0; j < 8; j++) {
            pg.b[j] = (__bf16)fmaf(vd[j], sl, aG[j]);
            pm.b[j] = (__bf16)(aS[j] * rd);
        }
        *(uint4*)(aggGb + (size_t)d * 128 + c8) = pg.u;
        *(uint4*)(meanb + (size_t)d * 128 + c8) = pm.u;
    }
}

// ---------------------------------------------------------------------------
// Pre-MLP: h_bf16 = x_f32 @ pre_w + pre_b, via MFMA; pre_w staged in LDS.
// ---------------------------------------------------------------------------
__global__ __launch_bounds__(256) void pre_gemm_mfma(
    const float* __restrict__ x, const __bf16* __restrict__ Wp0,
    const float* __restrict__ pre_b, __bf16* __restrict__ hb, int n)
{
    __shared__ __bf16 wlds[WPM];               // 32 KB
    const int tid  = threadIdx.x;
    const int w    = tid >> 6;
    const int lane = tid & 63;
    const int r0 = blockIdx.x * 64 + w * 16;
    int rl = r0 + (lane & 15);
    if (rl >= n) rl = n - 1;
    const int kg = lane >> 4;

    {
        uint4* lds4 = (uint4*)wlds;
        const uint4* g = (const uint4*)Wp0;
        #pragma unroll
        for (int it = 0; it < 8; it++)
            lds4[it * 256 + tid] = g[it * 256 + tid];
    }

    f32x4 acc[8];
    #pragma unroll
    for (int cb = 0; cb < 8; cb++) acc[cb] = (f32x4)(0.f);

    v8bf af[4];
    #pragma unroll
    for (int kc = 0; kc < 4; kc++) {
        const float* ap = x + (size_t)rl * 128 + kc * 32 + kg * 8;
        float4 a0 = *(const float4*)ap;
        float4 a1 = *(const float4*)(ap + 4);
        v8bf v;
        v[0] = (__bf16)a0.x; v[1] = (__bf16)a0.y;
        v[2] = (__bf16)a0.z; v[3] = (__bf16)a0.w;
        v[4] = (__bf16)a1.x; v[5] = (__bf16)a1.y;
        v[6] = (__bf16)a1.z; v[7] = (__bf16)a1.w;
        af[kc] = v;
    }
    __syncthreads();

    #pragma unroll
    for (int kc = 0; kc < 4; kc++) {
        #pragma unroll
        for (int cb = 0; cb < 8; cb++) {
            int bo = ((kc * 8 + cb) * 64 + lane) * 8;
            acc[cb] = __builtin_amdgcn_mfma_f32_16x16x32_bf16(
                af[kc], *(const v8bf*)&wlds[bo], acc[cb], 0, 0, 0);
        }
    }
    int cl = lane & 15;
    #pragma unroll
    for (int cb = 0; cb < 8; cb++) {
        float bias = pre_b[cb * 16 + cl];
        #pragma unroll
        for (int j = 0; j < 4; j++) {
            int r = r0 + kg * 4 + j;
            if (r < n) hb[(size_t)r * 128 + cb * 16 + cl] = (__bf16)(acc[cb][j] + bias);
        }
    }
}

// ---------------------------------------------------------------------------
// LAYER GEMM: 128 rows per block (512 threads, 8 waves). Single K=384 MFMA
// stream (conv softmax folded into weights), B-fragments staged in LDS
// (two 48KB phases, 6 uint4/thread each). Then LN blend + act blend.
// ---------------------------------------------------------------------------
__global__ __launch_bounds__(512, 4) void layer_gemm_kernel(
    const __bf16* __restrict__ aggGb, const __bf16* __restrict__ hin,
    const __bf16* __restrict__ meanb,
    const __bf16* __restrict__ WpG, const __bf16* __restrict__ WpS,
    const __bf16* __restrict__ WpN,
    const float* __restrict__ gcn_b,
    const float* __restrict__ lng, const float* __restrict__ lnb,
    const float* __restrict__ anorm, const float* __restrict__ aact,
    const float* __restrict__ aconv,
    __bf16* __restrict__ hout, int n)
{
    __shared__ __bf16 wlds[3 * 16 * 64 * 8];   // 48 KB
    const int tid  = threadIdx.x;
    const int w    = tid >> 6;                 // 0..7
    const int lane = tid & 63;
    const int r0 = blockIdx.x * 128 + w * 16;
    int rl = r0 + (lane & 15);
    if (rl >= n) rl = n - 1;
    const int kg = lane >> 4;

    v8bf af[12];
    #pragma unroll
    for (int kc = 0; kc < 4; kc++) {
        size_t ao = (size_t)rl * 128 + kc * 32 + kg * 8;
        af[kc]     = *(const v8bf*)(aggGb + ao);
        af[4 + kc] = *(const v8bf*)(hin   + ao);
        af[8 + kc] = *(const v8bf*)(meanb + ao);
    }

    f32x4 acc[8];
    #pragma unroll
    for (int cb = 0; cb < 8; cb++) acc[cb] = (f32x4)(0.f);

    uint4* lds4 = (uint4*)wlds;

    {
        const uint4* gG = (const uint4*)WpG;
        const uint4* gS = (const uint4*)WpS;
        const uint4* gN = (const uint4*)WpN;
        #pragma unroll
        for (int it = 0; it < 6; it++) {
            int idx = it * 512 + tid;          // 0..3071
            int m = idx >> 10;
            int r = idx & 1023;
            const uint4* g = (m == 0) ? gG : (m == 1) ? gS : gN;
            lds4[idx] = g[r];
        }
    }
    __syncthreads();
    #pragma unroll
    for (int kc2 = 0; kc2 < 2; kc2++) {
        #pragma unroll
        for (int cb = 0; cb < 8; cb++) {
            int bo = ((kc2 * 8 + cb) * 64 + lane) * 8;
            acc[cb] = __builtin_amdgcn_mfma_f32_16x16x32_bf16(
                af[kc2], *(const v8bf*)&wlds[bo], acc[cb], 0, 0, 0);
            acc[cb] = __builtin_amdgcn_mfma_f32_16x16x32_bf16(
                af[4 + kc2], *(const v8bf*)&wlds[8192 + bo], acc[cb], 0, 0, 0);
            acc[cb] = __builtin_amdgcn_mfma_f32_16x16x32_bf16(
                af[8 + kc2], *(const v8bf*)&wlds[16384 + bo], acc[cb], 0, 0, 0);
        }
    }
    __syncthreads();

    {
        const uint4* gG = (const uint4*)WpG + 1024;
        const uint4* gS = (const uint4*)WpS + 1024;
        const uint4* gN = (const uint4*)WpN + 1024;
        #pragma unroll
        for (int it = 0; it < 6; it++) {
            int idx = it * 512 + tid;
            int m = idx >> 10;
            int r = idx & 1023;
            const uint4* g = (m == 0) ? gG : (m == 1) ? gS : gN;
            lds4[idx] = g[r];
        }
    }
    __syncthreads();
    #pragma unroll
    for (int kc2 = 0; kc2 < 2; kc2++) {
        #pragma unroll
        for (int cb = 0; cb < 8; cb++) {
            int bo = ((kc2 * 8 + cb) * 64 + lane) * 8;
            acc[cb] = __builtin_amdgcn_mfma_f32_16x16x32_bf16(
                af[2 + kc2], *(const v8bf*)&wlds[bo], acc[cb], 0, 0, 0);
            acc[cb] = __builtin_amdgcn_mfma_f32_16x16x32_bf16(
                af[6 + kc2], *(const v8bf*)&wlds[8192 + bo], acc[cb], 0, 0, 0);
            acc[cb] = __builtin_amdgcn_mfma_f32_16x16x32_bf16(
                af[10 + kc2], *(const v8bf*)&wlds[16384 + bo], acc[cb], 0, 0, 0);
        }
    }

    float c0 = aconv[0], c1 = aconv[1];
    float m = fmaxf(c0, c1);
    float e0 = __expf(c0 - m), e1 = __expf(c1 - m);
    float wc0 = e0 / (e0 + e1);
    float q0 = anorm[0], q1 = anorm[1];
    m = fmaxf(q0, q1);
    e0 = __expf(q0 - m); e1 = __expf(q1 - m);
    float wn0 = e0 / (e0 + e1), wn1 = 1.f - wn0;
    float a0 = aact[0], a1 = aact[1], a2 = aact[2];
    m = fmaxf(fmaxf(a0, a1), a2);
    float f0 = __expf(a0 - m), f1 = __expf(a1 - m), f2 = __expf(a2 - m);
    float fs = 1.f / (f0 + f1 + f2);
    float wa0 = f0 * fs, wa1 = f1 * fs, wa2 = f2 * fs;

    int cl = lane & 15;
    float gbF[8], lg[8], lb[8];
    #pragma unroll
    for (int cb = 0; cb < 8; cb++) {
        int c = cb * 16 + cl;
        gbF[cb] = wc0 * gcn_b[c]; lg[cb] = lng[c]; lb[cb] = lnb[c];
    }

    float s[4] = {0, 0, 0, 0}, s2[4] = {0, 0, 0, 0};
    #pragma unroll
    for (int cb = 0; cb < 8; cb++)
        #pragma unroll
        for (int j = 0; j < 4; j++) {
            float tv = acc[cb][j] + gbF[cb];
            acc[cb][j] = tv;
            s[j] += tv;
            s2[j] = fmaf(tv, tv, s2[j]);
        }
    #pragma unroll
    for (int o = 1; o < 16; o <<= 1)
        #pragma unroll
        for (int j = 0; j < 4; j++) {
            s[j]  += __shfl_xor(s[j], o);
            s2[j] += __shfl_xor(s2[j], o);
        }
    float mu[4], rs[4];
    #pragma unroll
    for (int j = 0; j < 4; j++) {
        mu[j] = s[j] * (1.f / 128.f);
        float var = s2[j] * (1.f / 128.f) - mu[j] * mu[j];
        rs[j] = rsqrtf(var + EPSV);
    }

    #pragma unroll
    for (int j = 0; j < 4; j++) {
        int r = r0 + kg * 4 + j;
        if (r >= n) continue;
        #pragma unroll
        for (int cb = 0; cb < 8; cb++) {
            float tv = acc[cb][j];
            float ln = (tv - mu[j]) * rs[j] * lg[cb] + lb[cb];
            float hv = wn0 * ln + wn1 * tv;
            float rl_ = fmaxf(hv, 0.f);
            float ex2 = __expf(2.f * hv);
            float th = 1.f - 2.f * __builtin_amdgcn_rcpf(ex2 + 1.f);
            float el = hv > 0.f ? hv : __expf(hv) - 1.f;
            float out = wa0 * rl_ + wa1 * th + wa2 * el;
            hout[(size_t)r * 128 + cb * 16 + cl] = (__bf16)out;
        }
    }
}

// ---------------------------------------------------------------------------
// Pooling: sum h1+h2 (bf16), batch sorted -> run-length accumulate.
// ---------------------------------------------------------------------------
__global__ __launch_bounds__(256) void pool_sum_kernel(
    const __bf16* __restrict__ h1, const __bf16* __restrict__ h2,
    const int* __restrict__ batch, float* __restrict__ pooled, int n)
{
    int c2  = (threadIdx.x & 63) * 2;
    int seg = threadIdx.x >> 6;
    int n0  = blockIdx.x * 128 + seg * 32;
    int g_cur = -1;
    float acc0 = 0.f, acc1 = 0.f;
    for (int i = 0; i < 32; i++) {
        int node = n0 + i;
        if (node >= n) break;
        int g = batch[node];
        if (g != g_cur) {
            if (g_cur >= 0) {
                atomicAdd(&pooled[(size_t)g_cur * 128 + c2], acc0);
                atomicAdd(&pooled[(size_t)g_cur * 128 + c2 + 1], acc1);
            }
            g_cur = g; acc0 = 0.f; acc1 = 0.f;
        }
        unsigned u1 = *(const unsigned*)(h1 + (size_t)node * 128 + c2);
        unsigned u2 = *(const unsigned*)(h2 + (size_t)node * 128 + c2);
        acc0 += bf_lo(u1) + bf_lo(u2);
        acc1 += bf_hi(u1) + bf_hi(u2);
    }
    if (g_cur >= 0) {
        atomicAdd(&pooled[(size_t)g_cur * 128 + c2], acc0);
        atomicAdd(&pooled[(size_t)g_cur * 128 + c2 + 1], acc1);
    }
}

__global__ __launch_bounds__(64) void post_gemm_kernel(
    const float* __restrict__ pooled, const float* __restrict__ W,
    const float* __restrict__ b, float* __restrict__ out)
{
    __shared__ float p_s[128];
    int g = blockIdx.x;
    int j = threadIdx.x;
    p_s[j]      = pooled[(size_t)g * 128 + j];
    p_s[j + 64] = pooled[(size_t)g * 128 + 64 + j];
    __syncthreads();
    float acc = b[j];
    #pragma unroll
    for (int k = 0; k < 128; k++)
        acc = fmaf(p_s[k], W[k * 64 + j], acc);
    out[(size_t)g * 64 + j] = acc;
}

// ---------------------------------------------------------------------------
extern "C" void kernel_launch(void* const* d_in, const int* in_sizes, int n_in,
                              void* d_out, int out_size, void* d_ws, size_t ws_size,
                              hipStream_t stream)
{
    const float* x       = (const float*)d_in[0];
    const int*   ei      = (const int*)d_in[1];
    const int*   batch   = (const int*)d_in[2];
    const float* pre_w   = (const float*)d_in[3];
    const float* pre_b   = (const float*)d_in[4];
    const float* post_w  = (const float*)d_in[5];
    const float* post_b  = (const float*)d_in[6];
    const float* gcn_w   = (const float*)d_in[7];
    const float* gcn_b   = (const float*)d_in[8];
    const float* sage_ws = (const float*)d_in[9];
    const float* sage_wn = (const float*)d_in[10];
    const float* ln_g    = (const float*)d_in[11];
    const float* ln_b    = (const float*)d_in[12];
    const float* a_conv  = (const float*)d_in[13];
    const float* a_norm  = (const float*)d_in[14];
    const float* a_act   = (const float*)d_in[15];

    const int* src = ei;
    const int* dst = ei + N_EDGES;

    char* wsp = (char*)d_ws;
    size_t off = 0;
    auto alloc = [&](size_t bytes) {
        char* p = wsp + off;
        off += (bytes + 255) & ~(size_t)255;
        return p;
    };
    // h buffers carry one extra phantom row (index N_NODES, kept zero)
    const size_t NHB = (size_t)(N_NODES + 1) * 128 * sizeof(__bf16);
    __bf16*         hb0    = (__bf16*)alloc(NHB);
    __bf16*         h1b    = (__bf16*)alloc(NHB);
    __bf16*         h2b    = (__bf16*)alloc(NHB);
    __bf16*         aggGb  = (__bf16*)alloc(NHB);
    __bf16*         meanb  = (__bf16*)alloc(NHB);
    __bf16*         Wp     = (__bf16*)alloc((size_t)7 * WPM * sizeof(__bf16));
    int*            cnt    = (int*)alloc((N_NODES + 1) * sizeof(int));   // +sentinel
    unsigned short* csr    = (unsigned short*)alloc((size_t)N_NODES * CAP * sizeof(unsigned short));
    float*          pooled = (float*)alloc((size_t)G_GRAPHS * 128 * sizeof(float));

    const int PRE_BLOCKS   = (N_NODES + 63) / 64;          // 782
    const int LAYER_BLOCKS = (N_NODES + 127) / 128;        // 391
    const int GATHER_BLOCKS = (N_NODES + 3) / 4;
    const int SETUP_BLOCKS = (G_GRAPHS * 128 + 255) / 256; // covers all setup work
    const int FILL_BLOCKS  = ((N_EDGES + 255) / 256) * NSHARD;

    setup_kernel<<<SETUP_BLOCKS, 256, 0, stream>>>(
        pre_w, gcn_w, sage_ws, sage_wn, a_conv, Wp, cnt, pooled,
        (uint4*)(hb0 + (size_t)N_NODES * 128),
        (uint4*)(h1b + (size_t)N_NODES * 128));

    csr_fill_kernel<<<FILL_BLOCKS, 256, 0, stream>>>(
        src, dst, cnt, csr, N_EDGES);

    pre_gemm_mfma<<<PRE_BLOCKS, 256, 0, stream>>>(x, Wp, pre_b, hb0, N_NODES);

    const __bf16* hin[2]  = { hb0, h1b };
    __bf16*       hout[2] = { h1b, h2b };
    for (int l = 0; l < 2; l++) {
        fused_gather_bf16<<<GATHER_BLOCKS, 256, 0, stream>>>(
            hin[l], csr, cnt, aggGb, meanb, N_NODES);
        layer_gemm_kernel<<<LAYER_BLOCKS, 512, 0, stream>>>(
            aggGb, hin[l], meanb,
            Wp + (size_t)(1 + l) * WPM, Wp + (size_t)(3 + l) * WPM, Wp + (size_t)(5 + l) * WPM,
            gcn_b + l * 128, ln_g + l * 128, ln_b + l * 128,
            a_norm + l * 2, a_act + l * 3, a_conv + l * 2,
            hout[l], N_NODES);
    }

    pool_sum_kernel<<<(N_NODES + 127) / 128, 256, 0, stream>>>(h1b, h2b, batch, pooled, N_NODES);
    post_gemm_kernel<<<G_GRAPHS, 64, 0, stream>>>(pooled, post_w, post_b, (float*)d_out);
}

// Round 15
// 169.229 us; speedup vs baseline: 1.0450x; 1.0450x over previous
//
#include <hip/hip_runtime.h>
#include <hip/hip_fp16.h>
#include <math.h>

#define N_NODES 50000
#define N_EDGES 640000
#define HDIM    128
#define D_OUT   64
#define G_GRAPHS 500
#define EPSV    1e-5f
#define WPM     16384   // elements per packed 128x128 weight matrix
#define CAP     64      // bucket capacity (mean deg 12.8, P(deg>=64)~1e-24)
#define SENT    N_NODES // sentinel src id -> zero phantom row, cnt[SENT]=0
#define NSHARD  8       // dst shards, aligned with 8 XCDs (blockIdx%8 hint)
#define SHARD_SZ ((N_NODES + NSHARD - 1) / NSHARD)   // 6250

typedef __bf16 v8bf __attribute__((ext_vector_type(8)));
typedef float  f32x4 __attribute__((ext_vector_type(4)));

static __device__ __forceinline__ float bf_lo(unsigned u) {
    union { unsigned x; float f; } c; c.x = u << 16; return c.f;
}
static __device__ __forceinline__ float bf_hi(unsigned u) {
    union { unsigned x; float f; } c; c.x = u & 0xffff0000u; return c.f;
}

// ---------------------------------------------------------------------------
// Setup: zero cnt (incl. cnt[SENT]), zero phantom h rows, AND pack 7 f32
// 128x128 weights into bf16 MFMA B-fragment order with conv-softmax folded:
//   m=0: pre_w   m=1,2: wc0[l]*gcn_w[l]  m=3,4: wc1[l]*sage_ws[l]
//   m=5,6: wc1[l]*sage_wn[l]
// ---------------------------------------------------------------------------
__global__ void setup_kernel(const float* __restrict__ pre_w,
                             const float* __restrict__ gcn_w,
                             const float* __restrict__ sws,
                             const float* __restrict__ swn,
                             const float* __restrict__ a_conv,
                             __bf16* __restrict__ Wp,
                             int* __restrict__ cnt,
                             uint4* __restrict__ hrow0,
                             uint4* __restrict__ hrow1)
{
    int t = blockIdx.x * blockDim.x + threadIdx.x;
    if (t <= N_NODES) cnt[t] = 0;             // includes sentinel slot
    if (t < 16) {  // zero phantom row N of hb0 and h1b (256B each)
        hrow0[t] = make_uint4(0, 0, 0, 0);
        hrow1[t] = make_uint4(0, 0, 0, 0);
    }
    if (t >= 7 * 2048) return;
    int m    = t >> 11;
    int r    = t & 2047;
    int lane = r & 63;
    int fb   = r >> 6;           // kc*8 + cb
    int kc   = fb >> 3;
    int cb   = fb & 7;
    const float* W = pre_w;
    float scale = 1.f;
    if (m > 0) {
        int type = (m - 1) >> 1;     // 0=gcn, 1=sage_ws, 2=sage_wn
        int l    = (m - 1) & 1;
        float c0 = a_conv[l * 2], c1 = a_conv[l * 2 + 1];
        float mx = fmaxf(c0, c1);
        float e0 = __expf(c0 - mx), e1 = __expf(c1 - mx);
        float wc0 = e0 / (e0 + e1);
        scale = (type == 0) ? wc0 : (1.f - wc0);
        W = (type == 0) ? gcn_w + (size_t)l * WPM
          : (type == 1) ? sws   + (size_t)l * WPM
                        : swn   + (size_t)l * WPM;
    }
    int k0  = kc * 32 + (lane >> 4) * 8;
    int col = cb * 16 + (lane & 15);
    __bf16* out = Wp + (size_t)m * WPM + ((size_t)fb * 64 + lane) * 8;
    #pragma unroll
    for (int i = 0; i < 8; i++)
        out[i] = (__bf16)(scale * W[(size_t)(k0 + i) * 128 + col]);
}

// ---------------------------------------------------------------------------
// XCD-sharded direct-bucket CSR fill (2-byte entries, no counting pass).
// Blocks 8i..8i+7 process edge chunk i; block 8i+s writes only dst-shard s.
// ---------------------------------------------------------------------------
__global__ void csr_fill_kernel(const int* __restrict__ src, const int* __restrict__ dst,
                                int* __restrict__ cnt,
                                unsigned short* __restrict__ csr, int E) {
    int chunk = blockIdx.x >> 3;
    int shard = blockIdx.x & 7;
    int e = chunk * 256 + threadIdx.x;
    if (e >= E) return;
    int d = dst[e];
    if (d / SHARD_SZ != shard) return;
    int s = src[e];
    int pos = atomicAdd(&cnt[d], 1);
    csr[(d << 6) + pos] = (unsigned short)s;
}

// ---------------------------------------------------------------------------
// Pull-gather (bf16): one wave per dst node, direct buckets, unmasked main
// loop + single masked tail iteration. dinv computed inline from cnt.
// ---------------------------------------------------------------------------
__global__ __launch_bounds__(256) void fused_gather_bf16(
    const __bf16* __restrict__ hb,
    const unsigned short* __restrict__ csr,
    const int* __restrict__ cnt,
    __bf16* __restrict__ aggGb,
    __bf16* __restrict__ meanb, int n)
{
    int w = threadIdx.x >> 6;
    int lane = threadIdx.x & 63;
    int d = blockIdx.x * 4 + w;
    if (d >= n) return;
    int c = cnt[d];
    float cf = (float)c;
    float did = rsqrtf(cf + 1.0f);
    float rd  = 1.0f / fmaxf(cf, 1.0f);
    int base = d << 6;
    int full = c >> 4;          // unmasked 16-edge iterations
    int q  = lane >> 4;
    int c8 = (lane & 15) * 8;

    float aG[8] = {0, 0, 0, 0, 0, 0, 0, 0};
    float aS[8] = {0, 0, 0, 0, 0, 0, 0, 0};

    for (int p = 0; p < full; p++) {
        int s[4];
        #pragma unroll
        for (int k = 0; k < 4; k++)
            s[k] = csr[base + p * 16 + 4 * k + q];
        uint4 u[4];
        float ds[4];
        #pragma unroll
        for (int k = 0; k < 4; k++) {
            u[k]  = *(const uint4*)(hb + (size_t)s[k] * 128 + c8);
            ds[k] = rsqrtf((float)cnt[s[k]] + 1.0f);
        }
        #pragma unroll
        for (int k = 0; k < 4; k++) {
            float wk = ds[k] * did;
            float v[8] = { bf_lo(u[k].x), bf_hi(u[k].x), bf_lo(u[k].y), bf_hi(u[k].y),
                           bf_lo(u[k].z), bf_hi(u[k].z), bf_lo(u[k].w), bf_hi(u[k].w) };
            #pragma unroll
            for (int j = 0; j < 8; j++) {
                aG[j] = fmaf(v[j], wk, aG[j]);
                aS[j] += v[j];
            }
        }
    }
    if (c & 15) {   // masked tail: SENT -> zero phantom row, cnt[SENT]=0
        int s[4];
        #pragma unroll
        for (int k = 0; k < 4; k++) {
            int idx = full * 16 + 4 * k + q;
            s[k] = (idx < c) ? (int)csr[base + idx] : SENT;
        }
        uint4 u[4];
        float ds[4];
        #pragma unroll
        for (int k = 0; k < 4; k++) {
            u[k]  = *(const uint4*)(hb + (size_t)s[k] * 128 + c8);
            ds[k] = rsqrtf((float)cnt[s[k]] + 1.0f);
        }
        #pragma unroll
        for (int k = 0; k < 4; k++) {
            float wk = ds[k] * did;
            float v[8] = { bf_lo(u[k].x), bf_hi(u[k].x), bf_lo(u[k].y), bf_hi(u[k].y),
                           bf_lo(u[k].z), bf_hi(u[k].z), bf_lo(u[k].w), bf_hi(u[k].w) };
            #pragma unroll
            for (int j = 0; j < 8; j++) {
                aG[j] = fmaf(v[j], wk, aG[j]);
                aS[j] += v[j];
            }
        }
    }
    #pragma unroll
    for (int j = 0; j < 8; j++) {
        aG[j] += __shfl_xor(aG[j], 16);
        aG[j] += __shfl_xor(aG[j], 32);
        aS[j] += __shfl_xor(aS[j], 16);
        aS[j] += __shfl_xor(aS[j], 32);
    }
    if (q == 0) {
        uint4 ud = *(const uint4*)(hb + (size_t)d * 128 + c8);
        float vd[8] = { bf_lo(ud.x), bf_hi(ud.x), bf_lo(ud.y), bf_hi(ud.y),
                        bf_lo(ud.z), bf_hi(ud.z), bf_lo(ud.w), bf_hi(ud.w) };
        float sl = did * did;
        union { __bf16 b[8]; uint4 u; } pg, pm;
        #pragma unroll
        for (int j = 0; j < 8; j++) {
            pg.b[j] = (__bf16)fmaf(vd[j], sl, aG[j]);
            pm.b[j] = (__bf16)(aS[j] * rd);
        }
        *(uint4*)(aggGb + (size_t)d * 128 + c8) = pg.u;
        *(uint4*)(meanb + (size_t)d * 128 + c8) = pm.u;
    }
}

// ---------------------------------------------------------------------------
// Pre-MLP: h_bf16 = x_f32 @ pre_w + pre_b, via MFMA; pre_w staged in LDS.
// ---------------------------------------------------------------------------
__global__ __launch_bounds__(256) void pre_gemm_mfma(
    const float* __restrict__ x, const __bf16* __restrict__ Wp0,
    const float* __restrict__ pre_b, __bf16* __restrict__ hb, int n)
{
    __shared__ __bf16 wlds[WPM];               // 32 KB
    const int tid  = threadIdx.x;
    const int w    = tid >> 6;
    const int lane = tid & 63;
    const int r0 = blockIdx.x * 64 + w * 16;
    int rl = r0 + (lane & 15);
    if (rl >= n) rl = n - 1;
    const int kg = lane >> 4;

    {
        uint4* lds4 = (uint4*)wlds;
        const uint4* g = (const uint4*)Wp0;
        #pragma unroll
        for (int it = 0; it < 8; it++)
            lds4[it * 256 + tid] = g[it * 256 + tid];
    }

    f32x4 acc[8];
    #pragma unroll
    for (int cb = 0; cb < 8; cb++) acc[cb] = (f32x4)(0.f);

    v8bf af[4];
    #pragma unroll
    for (int kc = 0; kc < 4; kc++) {
        const float* ap = x + (size_t)rl * 128 + kc * 32 + kg * 8;
        float4 a0 = *(const float4*)ap;
        float4 a1 = *(const float4*)(ap + 4);
        v8bf v;
        v[0] = (__bf16)a0.x; v[1] = (__bf16)a0.y;
        v[2] = (__bf16)a0.z; v[3] = (__bf16)a0.w;
        v[4] = (__bf16)a1.x; v[5] = (__bf16)a1.y;
        v[6] = (__bf16)a1.z; v[7] = (__bf16)a1.w;
        af[kc] = v;
    }
    __syncthreads();

    #pragma unroll
    for (int kc = 0; kc < 4; kc++) {
        #pragma unroll
        for (int cb = 0; cb < 8; cb++) {
            int bo = ((kc * 8 + cb) * 64 + lane) * 8;
            acc[cb] = __builtin_amdgcn_mfma_f32_16x16x32_bf16(
                af[kc], *(const v8bf*)&wlds[bo], acc[cb], 0, 0, 0);
        }
    }
    int cl = lane & 15;
    #pragma unroll
    for (int cb = 0; cb < 8; cb++) {
        float bias = pre_b[cb * 16 + cl];
        #pragma unroll
        for (int j = 0; j < 4; j++) {
            int r = r0 + kg * 4 + j;
            if (r < n) hb[(size_t)r * 128 + cb * 16 + cl] = (__bf16)(acc[cb][j] + bias);
        }
    }
}

// ---------------------------------------------------------------------------
// LAYER GEMM: 128 rows per block (512 threads, 8 waves). Single K=384 MFMA
// stream (conv softmax folded into weights), B-fragments staged in LDS
// (two 48KB phases). Then LN blend + act blend.
// ---------------------------------------------------------------------------
__global__ __launch_bounds__(512, 4) void layer_gemm_kernel(
    const __bf16* __restrict__ aggGb, const __bf16* __restrict__ hin,
    const __bf16* __restrict__ meanb,
    const __bf16* __restrict__ WpG, const __bf16* __restrict__ WpS,
    const __bf16* __restrict__ WpN,
    const float* __restrict__ gcn_b,
    const float* __restrict__ lng, const float* __restrict__ lnb,
    const float* __restrict__ anorm, const float* __restrict__ aact,
    const float* __restrict__ aconv,
    __bf16* __restrict__ hout, int n)
{
    __shared__ __bf16 wlds[3 * 16 * 64 * 8];   // 48 KB
    const int tid  = threadIdx.x;
    const int w    = tid >> 6;                 // 0..7
    const int lane = tid & 63;
    const int r0 = blockIdx.x * 128 + w * 16;
    int rl = r0 + (lane & 15);
    if (rl >= n) rl = n - 1;
    const int kg = lane >> 4;

    v8bf af[12];
    #pragma unroll
    for (int kc = 0; kc < 4; kc++) {
        size_t ao = (size_t)rl * 128 + kc * 32 + kg * 8;
        af[kc]     = *(const v8bf*)(aggGb + ao);
        af[4 + kc] = *(const v8bf*)(hin   + ao);
        af[8 + kc] = *(const v8bf*)(meanb + ao);
    }

    f32x4 acc[8];
    #pragma unroll
    for (int cb = 0; cb < 8; cb++) acc[cb] = (f32x4)(0.f);

    uint4* lds4 = (uint4*)wlds;

    {
        const uint4* gG = (const uint4*)WpG;
        const uint4* gS = (const uint4*)WpS;
        const uint4* gN = (const uint4*)WpN;
        #pragma unroll
        for (int it = 0; it < 6; it++) {
            int idx = it * 512 + tid;          // 0..3071
            int m = idx >> 10;
            int r = idx & 1023;
            const uint4* g = (m == 0) ? gG : (m == 1) ? gS : gN;
            lds4[idx] = g[r];
        }
    }
    __syncthreads();
    #pragma unroll
    for (int kc2 = 0; kc2 < 2; kc2++) {
        #pragma unroll
        for (int cb = 0; cb < 8; cb++) {
            int bo = ((kc2 * 8 + cb) * 64 + lane) * 8;
            acc[cb] = __builtin_amdgcn_mfma_f32_16x16x32_bf16(
                af[kc2], *(const v8bf*)&wlds[bo], acc[cb], 0, 0, 0);
            acc[cb] = __builtin_amdgcn_mfma_f32_16x16x32_bf16(
                af[4 + kc2], *(const v8bf*)&wlds[8192 + bo], acc[cb], 0, 0, 0);
            acc[cb] = __builtin_amdgcn_mfma_f32_16x16x32_bf16(
                af[8 + kc2], *(const v8bf*)&wlds[16384 + bo], acc[cb], 0, 0, 0);
        }
    }
    __syncthreads();

    {
        const uint4* gG = (const uint4*)WpG + 1024;
        const uint4* gS = (const uint4*)WpS + 1024;
        const uint4* gN = (const uint4*)WpN + 1024;
        #pragma unroll
        for (int it = 0; it < 6; it++) {
            int idx = it * 512 + tid;
            int m = idx >> 10;
            int r = idx & 1023;
            const uint4* g = (m == 0) ? gG : (m == 1) ? gS : gN;
            lds4[idx] = g[r];
        }
    }
    __syncthreads();
    #pragma unroll
    for (int kc2 = 0; kc2 < 2; kc2++) {
        #pragma unroll
        for (int cb = 0; cb < 8; cb++) {
            int bo = ((kc2 * 8 + cb) * 64 + lane) * 8;
            acc[cb] = __builtin_amdgcn_mfma_f32_16x16x32_bf16(
                af[2 + kc2], *(const v8bf*)&wlds[bo], acc[cb], 0, 0, 0);
            acc[cb] = __builtin_amdgcn_mfma_f32_16x16x32_bf16(
                af[6 + kc2], *(const v8bf*)&wlds[8192 + bo], acc[cb], 0, 0, 0);
            acc[cb] = __builtin_amdgcn_mfma_f32_16x16x32_bf16(
                af[10 + kc2], *(const v8bf*)&wlds[16384 + bo], acc[cb], 0, 0, 0);
        }
    }

    float c0 = aconv[0], c1 = aconv[1];
    float m = fmaxf(c0, c1);
    float e0 = __expf(c0 - m), e1 = __expf(c1 - m);
    float wc0 = e0 / (e0 + e1);
    float q0 = anorm[0], q1 = anorm[1];
    m = fmaxf(q0, q1);
    e0 = __expf(q0 - m); e1 = __expf(q1 - m);
    float wn0 = e0 / (e0 + e1), wn1 = 1.f - wn0;
    float a0 = aact[0], a1 = aact[1], a2 = aact[2];
    m = fmaxf(fmaxf(a0, a1), a2);
    float f0 = __expf(a0 - m), f1 = __expf(a1 - m), f2 = __expf(a2 - m);
    float fs = 1.f / (f0 + f1 + f2);
    float wa0 = f0 * fs, wa1 = f1 * fs, wa2 = f2 * fs;

    int cl = lane & 15;
    float gbF[8], lg[8], lb[8];
    #pragma unroll
    for (int cb = 0; cb < 8; cb++) {
        int c = cb * 16 + cl;
        gbF[cb] = wc0 * gcn_b[c]; lg[cb] = lng[c]; lb[cb] = lnb[c];
    }

    float s[4] = {0, 0, 0, 0}, s2[4] = {0, 0, 0, 0};
    #pragma unroll
    for (int cb = 0; cb < 8; cb++)
        #pragma unroll
        for (int j = 0; j < 4; j++) {
            float tv = acc[cb][j] + gbF[cb];
            acc[cb][j] = tv;
            s[j] += tv;
            s2[j] = fmaf(tv, tv, s2[j]);
        }
    #pragma unroll
    for (int o = 1; o < 16; o <<= 1)
        #pragma unroll
        for (int j = 0; j < 4; j++) {
            s[j]  += __shfl_xor(s[j], o);
            s2[j] += __shfl_xor(s2[j], o);
        }
    float mu[4], rs[4];
    #pragma unroll
    for (int j = 0; j < 4; j++) {
        mu[j] = s[j] * (1.f / 128.f);
        float var = s2[j] * (1.f / 128.f) - mu[j] * mu[j];
        rs[j] = rsqrtf(var + EPSV);
    }

    #pragma unroll
    for (int j = 0; j < 4; j++) {
        int r = r0 + kg * 4 + j;
        if (r >= n) continue;
        #pragma unroll
        for (int cb = 0; cb < 8; cb++) {
            float tv = acc[cb][j];
            float ln = (tv - mu[j]) * rs[j] * lg[cb] + lb[cb];
            float hv = wn0 * ln + wn1 * tv;
            float rl_ = fmaxf(hv, 0.f);
            float ex2 = __expf(2.f * hv);
            float th = 1.f - 2.f * __builtin_amdgcn_rcpf(ex2 + 1.f);
            float el = hv > 0.f ? hv : __expf(hv) - 1.f;
            float out = wa0 * rl_ + wa1 * th + wa2 * el;
            hout[(size_t)r * 128 + cb * 16 + cl] = (__bf16)out;
        }
    }
}

// ---------------------------------------------------------------------------
// Fused pooling + post-GEMM: one block per graph. batch is sorted ->
// binary-search the node range, 4 waves stride-accumulate h1+h2 (f32),
// LDS reduce to the 128-wide pooled row, then 64 threads do the 128x64
// matvec. No atomics, no pooled buffer, no separate pool kernel.
// ---------------------------------------------------------------------------
__global__ __launch_bounds__(256) void pool_post_kernel(
    const __bf16* __restrict__ h1, const __bf16* __restrict__ h2,
    const int* __restrict__ batch,
    const float* __restrict__ W, const float* __restrict__ b,
    float* __restrict__ out, int n)
{
    __shared__ float ps[4][128];
    __shared__ float pool_s[128];
    const int g   = blockIdx.x;
    const int tid = threadIdx.x;
    const int wv  = tid >> 6;
    const int lane = tid & 63;

    // lower_bound(g) and lower_bound(g+1) — all threads redundantly (L2-hot)
    int lo = 0, hi = n;
    while (lo < hi) { int mid = (lo + hi) >> 1; if (batch[mid] < g) lo = mid + 1; else hi = mid; }
    int beg = lo;
    hi = n;
    while (lo < hi) { int mid = (lo + hi) >> 1; if (batch[mid] < g + 1) lo = mid + 1; else hi = mid; }
    int end = lo;

    float a0 = 0.f, a1 = 0.f;
    for (int node = beg + wv; node < end; node += 4) {
        unsigned u1 = *(const unsigned*)(h1 + (size_t)node * 128 + lane * 2);
        unsigned u2 = *(const unsigned*)(h2 + (size_t)node * 128 + lane * 2);
        a0 += bf_lo(u1) + bf_lo(u2);
        a1 += bf_hi(u1) + bf_hi(u2);
    }
    ps[wv][lane * 2]     = a0;
    ps[wv][lane * 2 + 1] = a1;
    __syncthreads();
    if (tid < 128) pool_s[tid] = ps[0][tid] + ps[1][tid] + ps[2][tid] + ps[3][tid];
    __syncthreads();
    if (tid < 64) {
        float acc = b[tid];
        #pragma unroll
        for (int k = 0; k < 128; k++)
            acc = fmaf(pool_s[k], W[k * 64 + tid], acc);
        out[(size_t)g * 64 + tid] = acc;
    }
}

// ---------------------------------------------------------------------------
extern "C" void kernel_launch(void* const* d_in, const int* in_sizes, int n_in,
                              void* d_out, int out_size, void* d_ws, size_t ws_size,
                              hipStream_t stream)
{
    const float* x       = (const float*)d_in[0];
    const int*   ei      = (const int*)d_in[1];
    const int*   batch   = (const int*)d_in[2];
    const float* pre_w   = (const float*)d_in[3];
    const float* pre_b   = (const float*)d_in[4];
    const float* post_w  = (const float*)d_in[5];
    const float* post_b  = (const float*)d_in[6];
    const float* gcn_w   = (const float*)d_in[7];
    const float* gcn_b   = (const float*)d_in[8];
    const float* sage_ws = (const float*)d_in[9];
    const float* sage_wn = (const float*)d_in[10];
    const float* ln_g    = (const float*)d_in[11];
    const float* ln_b    = (const float*)d_in[12];
    const float* a_conv  = (const float*)d_in[13];
    const float* a_norm  = (const float*)d_in[14];
    const float* a_act   = (const float*)d_in[15];

    const int* src = ei;
    const int* dst = ei + N_EDGES;

    char* wsp = (char*)d_ws;
    size_t off = 0;
    auto alloc = [&](size_t bytes) {
        char* p = wsp + off;
        off += (bytes + 255) & ~(size_t)255;
        return p;
    };
    // h buffers carry one extra phantom row (index N_NODES, kept zero)
    const size_t NHB = (size_t)(N_NODES + 1) * 128 * sizeof(__bf16);
    __bf16*         hb0    = (__bf16*)alloc(NHB);
    __bf16*         h1b    = (__bf16*)alloc(NHB);
    __bf16*         h2b    = (__bf16*)alloc(NHB);
    __bf16*         aggGb  = (__bf16*)alloc(NHB);
    __bf16*         meanb  = (__bf16*)alloc(NHB);
    __bf16*         Wp     = (__bf16*)alloc((size_t)7 * WPM * sizeof(__bf16));
    int*            cnt    = (int*)alloc((N_NODES + 1) * sizeof(int));   // +sentinel
    unsigned short* csr    = (unsigned short*)alloc((size_t)N_NODES * CAP * sizeof(unsigned short));

    const int PRE_BLOCKS    = (N_NODES + 63) / 64;          // 782
    const int LAYER_BLOCKS  = (N_NODES + 127) / 128;        // 391
    const int GATHER_BLOCKS = (N_NODES + 3) / 4;
    const int SETUP_BLOCKS  = (N_NODES + 1 + 255) / 256;    // covers cnt + pack
    const int FILL_BLOCKS   = ((N_EDGES + 255) / 256) * NSHARD;

    setup_kernel<<<SETUP_BLOCKS, 256, 0, stream>>>(
        pre_w, gcn_w, sage_ws, sage_wn, a_conv, Wp, cnt,
        (uint4*)(hb0 + (size_t)N_NODES * 128),
        (uint4*)(h1b + (size_t)N_NODES * 128));

    csr_fill_kernel<<<FILL_BLOCKS, 256, 0, stream>>>(
        src, dst, cnt, csr, N_EDGES);

    pre_gemm_mfma<<<PRE_BLOCKS, 256, 0, stream>>>(x, Wp, pre_b, hb0, N_NODES);

    const __bf16* hin[2]  = { hb0, h1b };
    __bf16*       hout[2] = { h1b, h2b };
    for (int l = 0; l < 2; l++) {
        fused_gather_bf16<<<GATHER_BLOCKS, 256, 0, stream>>>(
            hin[l], csr, cnt, aggGb, meanb, N_NODES);
        layer_gemm_kernel<<<LAYER_BLOCKS, 512, 0, stream>>>(
            aggGb, hin[l], meanb,
            Wp + (size_t)(1 + l) * WPM, Wp + (size_t)(3 + l) * WPM, Wp + (size_t)(5 + l) * WPM,
            gcn_b + l * 128, ln_g + l * 128, ln_b + l * 128,
            a_norm + l * 2, a_act + l * 3, a_conv + l * 2,
            hout[l], N_NODES);
    }

    pool_post_kernel<<<G_GRAPHS, 256, 0, stream>>>(
        h1b, h2b, batch, post_w, post_b, (float*)d_out, N_NODES);
}